// Round 3
// baseline (309.545 us; speedup 1.0000x reference)
//
#include <hip/hip_runtime.h>
#include <math.h>

#define B_N 2048
#define KK 128
#define MM 640
#define HS 136    // k-stride (elems) for transposed bf16 B-panels (pad kills pow2 conflicts)
#define ZSS 40    // Z row stride (bf16)
#define ALPHA (1.0f/128.0f)
#define VARTHETA 0.1f
#define PMAXV 10.0f
#define BIGV 1000000000.0f

typedef __attribute__((ext_vector_type(8))) short short8;
typedef __attribute__((ext_vector_type(4))) float floatx4;

static __device__ __forceinline__ unsigned short f2bf(float f) {
    unsigned u = __builtin_bit_cast(unsigned, f);
    u += 0x7fffu + ((u >> 16) & 1u);           // RNE
    return (unsigned short)(u >> 16);
}
static __device__ __forceinline__ float bf2f(unsigned short h) {
    unsigned u = ((unsigned)h) << 16;
    return __builtin_bit_cast(float, u);
}

// LDS pool overlays:
//  poolA (10240 B): w1aT (8704, staging->MFMA1)  then  zb (10240, MFMA2->E)
//  poolB (8704 B) : colred (4096, phase1->g1) -> c2T (8704, MFMA1->MFMA2)
//                   -> eT(1360 @0) / dpred(4096 @2048) / diag(512 @6400)
#define POOLA_OFF 0
#define POOLB_OFF 10240
#define POOL_BYTES (10240 + 8704)

__global__ __launch_bounds__(512, 6)
void unfold_pocs_kernel(
    const int* __restrict__ num_itr_p, const int* __restrict__ kth_p,
    const float* __restrict__ HW, const float* __restrict__ x0,
    const float* __restrict__ nu3_p, const float* __restrict__ tg_p,
    const float* __restrict__ g1_W0a, const float* __restrict__ g1_W1a,
    const float* __restrict__ g1_W0b, const float* __restrict__ g1_W1b,
    const float* __restrict__ g2_W0a, const float* __restrict__ g2_W1a,
    const float* __restrict__ g2_W0b, const float* __restrict__ g2_W1b,
    float* __restrict__ out)
{
    __shared__ __align__(16) unsigned char pool[POOL_BYTES];
    __shared__ __align__(16) float xb[MM];
    __shared__ __align__(16) float scr8[KK*8];             // SX (phase1->g1), t0 (E->tilde)
    __shared__ __align__(16) float g1w0a[160], g1w1a[160];
    __shared__ __align__(16) float g1w0b[64],  g1w1b[64];
    __shared__ __align__(16) float w0a2b[160], w1a2b[160]; // bottom 5 rows of g2 W0a/W1a
    __shared__ __align__(16) float w0b2[160],  w1b2[160];  // 32x5
    __shared__ float red[16];

    unsigned short* w1aT  = (unsigned short*)(pool + POOLA_OFF);
    unsigned short* zbp   = (unsigned short*)(pool + POOLA_OFF);
    float*          colred= (float*)(pool + POOLB_OFF);
    unsigned short* c2T   = (unsigned short*)(pool + POOLB_OFF);
    unsigned short* eT    = (unsigned short*)(pool + POOLB_OFF);
    float*          dpred = (float*)(pool + POOLB_OFF + 2048);
    float*          diagl = (float*)(pool + POOLB_OFF + 6400);

    const int t = threadIdx.x;
    const int b = blockIdx.x;
    const float* HWb = HW + (size_t)b * (KK*KK);

    const int wv = t >> 6, lane = t & 63, quad = lane >> 4, lr = lane & 15;
    const int arow = wv*16 + lr;

    // ---------- staging ----------
    short8 A[4];                                // hw A-fragments, straight from HBM
    #pragma unroll
    for (int kt = 0; kt < 4; ++kt) {
        float4 f0 = *(const float4*)(HWb + arow*KK + kt*32 + quad*8);
        float4 f1 = *(const float4*)(HWb + arow*KK + kt*32 + quad*8 + 4);
        short8 a;
        a[0]=(short)f2bf(f0.x); a[1]=(short)f2bf(f0.y); a[2]=(short)f2bf(f0.z); a[3]=(short)f2bf(f0.w);
        a[4]=(short)f2bf(f1.x); a[5]=(short)f2bf(f1.y); a[6]=(short)f2bf(f1.z); a[7]=(short)f2bf(f1.w);
        A[kt] = a;
    }
    {   // W1a_top (128x32) -> transposed bf16, k-fastest (coalesced global, b128 LDS writes)
        const int n = t & 31, seg = t >> 5;     // 16 segs of 8 k
        unsigned short tmp[8];
        #pragma unroll
        for (int i = 0; i < 8; ++i) tmp[i] = f2bf(g2_W1a[(seg*8 + i)*32 + n]);
        *(short8*)&w1aT[n*HS + seg*8] = *(short8*)tmp;
    }
    if (t < 160) {
        *(float4*)(xb + t*4) = *(const float4*)(x0 + (size_t)b*MM + t*4);
        g1w0a[t] = g1_W0a[t];
        g1w1a[t] = g1_W1a[t];
        w0a2b[t] = g2_W0a[KK*32 + t];
        w1a2b[t] = g2_W1a[KK*32 + t];
        w0b2[t]  = g2_W0b[t];
        w1b2[t]  = g2_W1b[t];
    }
    if (t < 64) { g1w0b[t] = g1_W0b[t]; g1w1b[t] = g1_W1b[t]; }
    __syncthreads();

    // ---------- phase 1: SX = HW@X1 (MFMA) + colsum partials ----------
    {
        floatx4 acc = {0.f, 0.f, 0.f, 0.f};
        const int ns = lr < 5 ? lr : 4;
        #pragma unroll
        for (int kt = 0; kt < 4; ++kt) {
            float4 f0 = *(const float4*)(xb + ns*KK + kt*32 + quad*8);
            float4 f1 = *(const float4*)(xb + ns*KK + kt*32 + quad*8 + 4);
            short8 bb;
            bb[0]=(short)f2bf(f0.x); bb[1]=(short)f2bf(f0.y); bb[2]=(short)f2bf(f0.z); bb[3]=(short)f2bf(f0.w);
            bb[4]=(short)f2bf(f1.x); bb[5]=(short)f2bf(f1.y); bb[6]=(short)f2bf(f1.z); bb[7]=(short)f2bf(f1.w);
            acc = __builtin_amdgcn_mfma_f32_16x16x32_bf16(A[kt], bb, acc, 0, 0, 0);
        }
        if (lr < 5) {
            #pragma unroll
            for (int r = 0; r < 4; ++r)
                scr8[(wv*16 + quad*4 + r)*8 + lr] = acc[r];
        }
    }
    #pragma unroll
    for (int kt = 0; kt < 4; ++kt) {            // colsum: reduce rows over lr within quad
        float v[8];
        #pragma unroll
        for (int j = 0; j < 8; ++j) v[j] = bf2f((unsigned short)A[kt][j]);
        #pragma unroll
        for (int mk = 1; mk < 16; mk <<= 1)
            #pragma unroll
            for (int j = 0; j < 8; ++j) v[j] += __shfl_xor(v[j], mk);
        if (lr == 0) {
            float4 a0 = {v[0],v[1],v[2],v[3]}, a1 = {v[4],v[5],v[6],v[7]};
            *(float4*)&colred[wv*128 + kt*32 + quad*8]     = a0;
            *(float4*)&colred[wv*128 + kt*32 + quad*8 + 4] = a1;
        }
    }
    __syncthreads();

    const int row = t >> 2, g = t & 3;          // 4 lanes per row for row-ops

    // ---------- phase 2: g1 -> per-wave partials ----------
    {
        float sx[5], x1r[5];
        #pragma unroll
        for (int f = 0; f < 5; ++f) { sx[f] = scr8[row*8 + f]; x1r[f] = xb[f*KK + row]; }

        float zb0p0=0, zb0p1=0, zb1p0=0, zb1p1=0;
        #pragma unroll
        for (int hh = 0; hh < 8; ++hh) {
            int h = 8*g + hh;
            float a = 0.0f;
            #pragma unroll
            for (int f = 0; f < 5; ++f) a += x1r[f]*g1w0a[f*32+h] + sx[f]*g1w1a[f*32+h];
            a = fmaxf(a, 0.0f);
            zb0p0 += a * g1w0b[h*2+0];
            zb0p1 += a * g1w0b[h*2+1];
            zb1p0 += a * g1w1b[h*2+0];
            zb1p1 += a * g1w1b[h*2+1];
        }
        float msum = colred[(2*g)*128 + row] + colred[(2*g+1)*128 + row];
        msum += __shfl_xor(msum, 1); msum += __shfl_xor(msum, 2);
        float m = msum * (1.0f/KK);
        float c0 = zb0p0*(1.0f/KK) + m*zb1p0;
        float c1 = zb0p1*(1.0f/KK) + m*zb1p1;
        #pragma unroll
        for (int s = 1; s < 64; s <<= 1) { c0 += __shfl_xor(c0, s); c1 += __shfl_xor(c1, s); }
        if ((t & 63) == 0) { red[wv*2] = c0; red[wv*2 + 1] = c1; }
    }
    __syncthreads();

    // ---------- phase 3: lbd (redundant per-thread) + x update ----------
    {
        float lbd0 = 0.f, lbd1 = 0.f;
        #pragma unroll
        for (int w2 = 0; w2 < 8; ++w2) { lbd0 += red[w2*2]; lbd1 += red[w2*2+1]; }
        lbd0 = fmaxf(lbd0, 0.0f); lbd1 = fmaxf(lbd1, 0.0f);
        if (t < KK) {
            float s1v = xb[KK + t];
            xb[KK + t]   = s1v - lbd0 * (ALPHA / (1.0f + s1v));
            xb[4*KK + t] += lbd1 * (ALPHA * VARTHETA);
        }
    }
    __syncthreads();

    // ---------- phase 4: MFMA1: C2 = W0a_top + X2@W1a_bot + HW@W1a_top -> c2T ----------
    #pragma unroll
    for (int nt = 0; nt < 2; ++nt) {
        floatx4 acc = {0.f, 0.f, 0.f, 0.f};
        #pragma unroll
        for (int kt = 0; kt < 4; ++kt) {
            short8 bb = *(const short8*)&w1aT[(nt*16 + lr)*HS + kt*32 + quad*8];
            acc = __builtin_amdgcn_mfma_f32_16x16x32_bf16(A[kt], bb, acc, 0, 0, 0);
        }
        const int n = nt*16 + lr;
        unsigned short pe[4];
        #pragma unroll
        for (int r = 0; r < 4; ++r) {
            int mm = wv*16 + quad*4 + r;
            float v = acc[r] + g2_W0a[mm*32 + n];
            #pragma unroll
            for (int f = 0; f < 5; ++f) v += xb[f*KK + mm] * w1a2b[f*32 + n];
            pe[r] = f2bf(v);
        }
        if (nt == 0) __syncthreads();           // colred dead before first c2T write
        ushort4 p4; p4.x = pe[0]; p4.y = pe[1]; p4.z = pe[2]; p4.w = pe[3];
        *(ushort4*)&c2T[n*HS + wv*16 + quad*4] = p4;
    }
    __syncthreads();

    // ---------- phase 5: MFMA2: Z = relu(HW@C2 + X2@W0a_bot) -> zb ----------
    #pragma unroll
    for (int nt = 0; nt < 2; ++nt) {
        floatx4 acc = {0.f, 0.f, 0.f, 0.f};
        #pragma unroll
        for (int kt = 0; kt < 4; ++kt) {
            short8 bb = *(const short8*)&c2T[(nt*16 + lr)*HS + kt*32 + quad*8];
            acc = __builtin_amdgcn_mfma_f32_16x16x32_bf16(A[kt], bb, acc, 0, 0, 0);
        }
        const int n = nt*16 + lr;
        if (nt == 1) {                          // w1aT dead; zb shares poolA
            #pragma unroll
            for (int r = 0; r < 4; ++r) {
                int mm = wv*16 + quad*4 + r;
                float v = acc[r];
                #pragma unroll
                for (int f = 0; f < 5; ++f) v += xb[f*KK + mm] * w0a2b[f*32 + n];
                zbp[mm*ZSS + n] = f2bf(fmaxf(v, 0.0f));
            }
        } else {
            __syncthreads();                    // all MFMA1 reads of w1aT... (already done; c2T reads need no sync w/ zb) 
            #pragma unroll
            for (int r = 0; r < 4; ++r) {
                int mm = wv*16 + quad*4 + r;
                float v = acc[r];
                #pragma unroll
                for (int f = 0; f < 5; ++f) v += xb[f*KK + mm] * w0a2b[f*32 + n];
                zbp[mm*ZSS + n] = f2bf(fmaxf(v, 0.0f));
            }
        }
    }
    __syncthreads();

    // ---------- phase 6: E = Z@W1b2 -> eT, t0 = Z@W0b2 -> scr8 ----------
    {
        float ev[5] = {0,0,0,0,0}, t0v[5] = {0,0,0,0,0};
        short8 zrow = *(const short8*)&zbp[row*ZSS + g*8];
        #pragma unroll
        for (int hh = 0; hh < 8; ++hh) {
            int h = 8*g + hh;
            float zv = bf2f((unsigned short)zrow[hh]);
            #pragma unroll
            for (int c = 0; c < 5; ++c) {
                ev[c]  += zv * w1b2[h*5 + c];
                t0v[c] += zv * w0b2[h*5 + c];
            }
        }
        #pragma unroll
        for (int c = 0; c < 5; ++c) {
            ev[c]  += __shfl_xor(ev[c], 1);  ev[c]  += __shfl_xor(ev[c], 2);
            t0v[c] += __shfl_xor(t0v[c], 1); t0v[c] += __shfl_xor(t0v[c], 2);
        }
        if (g == 0) {
            #pragma unroll
            for (int c = 0; c < 5; ++c) {
                eT[c*HS + row]  = f2bf(ev[c]);
                scr8[row*8 + c] = t0v[c];
            }
        }
    }
    __syncthreads();

    // ---------- phase 7: tilde = t0 + HW@E ; x += tilde^T ----------
    {
        floatx4 acc = {0.f, 0.f, 0.f, 0.f};
        const int ns = lr < 5 ? lr : 4;
        #pragma unroll
        for (int kt = 0; kt < 4; ++kt) {
            short8 bb = *(const short8*)&eT[ns*HS + kt*32 + quad*8];
            acc = __builtin_amdgcn_mfma_f32_16x16x32_bf16(A[kt], bb, acc, 0, 0, 0);
        }
        if (lr < 5) {
            #pragma unroll
            for (int r = 0; r < 4; ++r) {
                int mm = wv*16 + quad*4 + r;
                xb[lr*KK + mm] += acc[r] + scr8[mm*8 + lr];
            }
        }
    }
    __syncthreads();

    // ---------- phase 8: f = sum(x[:K]) - PMAX (redundant per-thread) ----------
    float pv = (t < KK) ? xb[t] : 0.0f;
    #pragma unroll
    for (int s = 1; s < 64; s <<= 1) pv += __shfl_xor(pv, s);
    if ((t & 63) == 0) red[wv] = pv;
    __syncthreads();
    float fv = -PMAXV;
    #pragma unroll
    for (int w2 = 0; w2 < 8; ++w2) fv += red[w2];

    const int num_itr = num_itr_p[0], kth = kth_p[0];
    const bool flag = (kth == num_itr - 1);
    const float nu3 = nu3_p[0], tg = tg_p[0];
    const float onu = 1.0f + nu3, otg = 1.0f + tg;
    const float Vnu = 1.0f - 1.0f/(onu*onu), Vg = 1.0f - 1.0f/(otg*otg);
    float* outx = out + (size_t)b * MM;

    // ---------- phase 9: clamp + store ----------
    #pragma unroll
    for (int r2 = 0; r2 < 2; ++r2) {
        int idx = r2*512 + t;
        if (idx < MM) {
            float v = xb[idx];
            if (idx < KK && fv > 0.0f) v -= fv * (1.0f/KK);
            v = fmaxf(v, (idx >= KK   && idx < 2*KK) ? nu3 : 0.0f);
            v = fminf(v, (idx >= 2*KK && idx < 3*KK) ? tg  : BIGV);
            v = fmaxf(v, (idx >= 3*KK && idx < 4*KK) ? Vnu : 0.0f);
            v = fminf(v, (idx >= 3*KK && idx < 4*KK) ? Vg  : BIGV);
            if (flag) v = fmaxf(v, 0.0f);
            xb[idx] = v;
            outx[idx] = v;
        }
    }

    // ---------- phase 10: extra outputs (last iteration) ----------
    if (flag) {
        __syncthreads();
        const size_t O1 = (size_t)B_N*MM;
        const size_t OK = (size_t)B_N*KK;
        if (t < KK) {
            float xg = xb[2*KK + t], xv = xb[3*KK + t];
            float u1 = 1.0f + xg;
            out[O1 + (size_t)b*KK + t]      = 1.0f - 1.0f/(u1*u1) - xv;   // f5
            out[O1 + OK + (size_t)b*KK + t] = sqrtf(xv) - xb[4*KK + t];   // f6
        }
        {   // diag extract from A-fragments
            int kt_n = wv >> 1;
            int qexp = ((wv & 1) << 1) + (lr >> 3);
            if (quad == qexp) {
                short8 av = A[0];
                if (kt_n == 1) av = A[1];
                else if (kt_n == 2) av = A[2];
                else if (kt_n == 3) av = A[3];
                int j = lr & 7;
                float dv = 0.f;
                #pragma unroll
                for (int jj = 0; jj < 8; ++jj) if (jj == j) dv = bf2f((unsigned short)av[jj]);
                diagl[arow] = dv;
            }
        }
        {   // dp = p @ HW partials via shfl
            float p = xb[arow];
            #pragma unroll
            for (int kt = 0; kt < 4; ++kt) {
                float v[8];
                #pragma unroll
                for (int j = 0; j < 8; ++j) v[j] = p * bf2f((unsigned short)A[kt][j]);
                #pragma unroll
                for (int mk = 1; mk < 16; mk <<= 1)
                    #pragma unroll
                    for (int j = 0; j < 8; ++j) v[j] += __shfl_xor(v[j], mk);
                if (lr == 0) {
                    float4 a0 = {v[0],v[1],v[2],v[3]}, a1 = {v[4],v[5],v[6],v[7]};
                    *(float4*)&dpred[wv*128 + kt*32 + quad*8]     = a0;
                    *(float4*)&dpred[wv*128 + kt*32 + quad*8 + 4] = a1;
                }
            }
        }
        __syncthreads();
        {   // combine dp per row, emit f4/f2
            float ds = dpred[(2*g)*128 + row] + dpred[(2*g+1)*128 + row];
            ds += __shfl_xor(ds, 1); ds += __shfl_xor(ds, 2);
            if (g == 0) {
                float p_  = xb[row], nuv = xb[KK + row], xg = xb[2*KK + row];
                float top = p_ * diagl[row];
                float down = ds - top + 1.0f;
                out[O1 + 2*OK + (size_t)b*KK + row] = top - down * xg;    // f4
                out[O1 + 3*OK + (size_t)b*KK + row] = nuv * down - top;   // f2
            }
        }
    }
}

extern "C" void kernel_launch(void* const* d_in, const int* in_sizes, int n_in,
                              void* d_out, int out_size, void* d_ws, size_t ws_size,
                              hipStream_t stream) {
    unfold_pocs_kernel<<<dim3(B_N), dim3(512), 0, stream>>>(
        (const int*)d_in[0], (const int*)d_in[1],
        (const float*)d_in[2], (const float*)d_in[3],
        (const float*)d_in[4], (const float*)d_in[5],
        (const float*)d_in[12], (const float*)d_in[13],
        (const float*)d_in[14], (const float*)d_in[15],
        (const float*)d_in[16], (const float*)d_in[17],
        (const float*)d_in[18], (const float*)d_in[19],
        (float*)d_out);
}